// Round 4
// baseline (319.579 us; speedup 1.0000x reference)
//
#include <hip/hip_runtime.h>
#include <hip/hip_bf16.h>

// Problem constants (B=4, T=4096, D=1024). FP32 I/O, bf16 MFMA internally.
#define BB 4
#define TT 4096
#define DD 1024
#define MM (BB * TT)   // 16384 rows
#define LN_EPS 1e-5f

typedef __attribute__((ext_vector_type(8))) short bf16x8;   // 8 bf16 = 4 VGPRs
typedef __attribute__((ext_vector_type(4))) float f32x4;

__device__ __forceinline__ float bfbits2f(unsigned short h) {
    return __uint_as_float(((unsigned int)h) << 16);
}
__device__ __forceinline__ unsigned short f2bfbits(float f) {
    __hip_bfloat16 h = __float2bfloat16(f);
    return *reinterpret_cast<unsigned short*>(&h);
}
__device__ __forceinline__ unsigned int pack2(float a, float b) {
    return (unsigned int)f2bfbits(a) | ((unsigned int)f2bfbits(b) << 16);
}

// async global->LDS, 16B per lane (wave-uniform base + lane*16).
__device__ __forceinline__ void async_copy16(void* lds, const void* g) {
    __builtin_amdgcn_global_load_lds(
        (const __attribute__((address_space(1))) void*)g,
        (__attribute__((address_space(3))) void*)lds,
        16, 0, 0);
}

// ---------------------------------------------------------------------------
// fp32 -> bf16 conversion of the 3 weight matrices in ONE launch.
// grid 3072: blocks [0,1024) -> w0, [1024,2048) -> w1, [2048,3072) -> w2.
// ---------------------------------------------------------------------------
__global__ __launch_bounds__(256)
void convert_w3(const float* __restrict__ s0, const float* __restrict__ s1,
                const float* __restrict__ s2,
                __hip_bfloat16* __restrict__ d0, __hip_bfloat16* __restrict__ d1,
                __hip_bfloat16* __restrict__ d2)
{
    const int blk = blockIdx.x;
    const int w = blk >> 10;
    const float* src = (w == 0) ? s0 : (w == 1) ? s1 : s2;
    __hip_bfloat16* dst = (w == 0) ? d0 : (w == 1) ? d1 : d2;
    const size_t i = ((size_t)(blk & 1023) * 256 + threadIdx.x) * 4;
    float4 v = *(const float4*)(src + i);
    uint2 o;
    o.x = pack2(v.x, v.y);
    o.y = pack2(v.z, v.w);
    *(uint2*)((unsigned short*)dst + i) = o;
}

// ---------------------------------------------------------------------------
// LayerNorm: fp32 in -> bf16 out. One WAVE per row (4 rows / 256-thr block).
// Lane handles 16 consecutive d's: 64B loads, 32B packed stores, shuffle-only
// reduction (no LDS / syncthreads).
// ---------------------------------------------------------------------------
__global__ __launch_bounds__(256)
void ln_kernel(const float* __restrict__ x,
               const float* __restrict__ w,
               const float* __restrict__ b,
               __hip_bfloat16* __restrict__ out)
{
    const int wv   = threadIdx.x >> 6;
    const int lane = threadIdx.x & 63;
    const int row  = blockIdx.x * 4 + wv;

    const float* xr = x + (size_t)row * DD + lane * 16;
    float4 v[4];
    #pragma unroll
    for (int i = 0; i < 4; ++i) v[i] = *(const float4*)(xr + i * 4);

    float s = 0.0f, ss = 0.0f;
    #pragma unroll
    for (int i = 0; i < 4; ++i) {
        s  += (v[i].x + v[i].y) + (v[i].z + v[i].w);
        ss += fmaf(v[i].x, v[i].x, fmaf(v[i].y, v[i].y,
              fmaf(v[i].z, v[i].z, v[i].w * v[i].w)));
    }
    #pragma unroll
    for (int o = 32; o > 0; o >>= 1) {
        s  += __shfl_down(s, o);
        ss += __shfl_down(ss, o);
    }
    s  = __shfl(s, 0);
    ss = __shfl(ss, 0);

    const float mu   = s * (1.0f / DD);
    const float var  = ss * (1.0f / DD) - mu * mu;
    const float rstd = rsqrtf(var + LN_EPS);

    unsigned int res[8];
    #pragma unroll
    for (int i = 0; i < 4; ++i) {
        float4 wr = *(const float4*)(w + lane * 16 + i * 4);
        float4 br = *(const float4*)(b + lane * 16 + i * 4);
        float o0 = (v[i].x - mu) * rstd * wr.x + br.x;
        float o1 = (v[i].y - mu) * rstd * wr.y + br.y;
        float o2 = (v[i].z - mu) * rstd * wr.z + br.z;
        float o3 = (v[i].w - mu) * rstd * wr.w + br.w;
        res[i * 2]     = pack2(o0, o1);
        res[i * 2 + 1] = pack2(o2, o3);
    }
    unsigned short* op = (unsigned short*)out + (size_t)row * DD + lane * 16;
    *(uint4*)op       = make_uint4(res[0], res[1], res[2], res[3]);
    *(uint4*)(op + 8) = make_uint4(res[4], res[5], res[6], res[7]);
}

// ---------------------------------------------------------------------------
// Fused dual GEMM + gate:
//   g = A @ Wg^T + gb;  v = A @ Wv^T + vb;  U = (2*sigmoid(g)-1)*v
// OPERAND-SWAP epilogue: mfma(b_frag, a_frag, acc) yields, per lane:
//   m = lane&15, n = (lane>>4)*4 + reg  -> 4 consecutive n per lane
//   -> one packed 8B store per (i,j) instead of 4 scalar 2B stores.
// ---------------------------------------------------------------------------
__global__ __launch_bounds__(256, 2)
void dual_gemm_gate(const __hip_bfloat16* __restrict__ A,
                    const __hip_bfloat16* __restrict__ Wg,
                    const __hip_bfloat16* __restrict__ Wv,
                    const float* __restrict__ gb,
                    const float* __restrict__ vb,
                    __hip_bfloat16* __restrict__ U,
                    int M, int N, int K)
{
    constexpr int BK = 32;
    __shared__ short As[128 * BK];
    __shared__ short Bg[128 * BK];
    __shared__ short Bv[128 * BK];

    const int tid  = threadIdx.x;
    const int m0   = blockIdx.x * 128;
    const int n0   = blockIdx.y * 128;
    const int wave = tid >> 6;
    const int lane = tid & 63;
    const int wm   = (wave & 1) * 64;
    const int wn   = (wave >> 1) * 64;
    const int lrow = lane & 15;
    const int kgrp = lane >> 4;      // 0..3

    f32x4 accg[4][4] = {};
    f32x4 accv[4][4] = {};

    const int srow = tid >> 2;
    const int sc   = tid & 3;
    const __hip_bfloat16* ga0 = A  + (size_t)(m0 + srow) * K + sc * 8;
    const __hip_bfloat16* gg0 = Wg + (size_t)(n0 + srow) * K + sc * 8;
    const __hip_bfloat16* gv0 = Wv + (size_t)(n0 + srow) * K + sc * 8;

    for (int k0 = 0; k0 < K; k0 += BK) {
        #pragma unroll
        for (int r = 0; r < 2; ++r) {
            async_copy16(&As[(r * 256 + tid) * 8], ga0 + (size_t)r * 64 * K + k0);
            async_copy16(&Bg[(r * 256 + tid) * 8], gg0 + (size_t)r * 64 * K + k0);
            async_copy16(&Bv[(r * 256 + tid) * 8], gv0 + (size_t)r * 64 * K + k0);
        }
        __builtin_amdgcn_s_waitcnt(0);
        __syncthreads();

        bf16x8 af[4], bgf[4], bvf[4];
        #pragma unroll
        for (int i = 0; i < 4; ++i)
            af[i] = *(const bf16x8*)&As[(wm + i * 16 + lrow) * BK + kgrp * 8];
        #pragma unroll
        for (int j = 0; j < 4; ++j) {
            bgf[j] = *(const bf16x8*)&Bg[(wn + j * 16 + lrow) * BK + kgrp * 8];
            bvf[j] = *(const bf16x8*)&Bv[(wn + j * 16 + lrow) * BK + kgrp * 8];
        }

        // swapped operands: acc[i][j] holds the (m-tile i, n-tile j) block
        // with m = lane&15, n = kgrp*4 + reg
        #pragma unroll
        for (int i = 0; i < 4; ++i)
            #pragma unroll
            for (int j = 0; j < 4; ++j) {
                accg[i][j] = __builtin_amdgcn_mfma_f32_16x16x32_bf16(
                    bgf[j], af[i], accg[i][j], 0, 0, 0);
                accv[i][j] = __builtin_amdgcn_mfma_f32_16x16x32_bf16(
                    bvf[j], af[i], accv[i][j], 0, 0, 0);
            }
        __syncthreads();
    }

    #pragma unroll
    for (int j = 0; j < 4; ++j) {
        const int nb = n0 + wn + j * 16 + kgrp * 4;
        const float4 gb4 = *(const float4*)(gb + nb);
        const float4 vb4 = *(const float4*)(vb + nb);
        #pragma unroll
        for (int i = 0; i < 4; ++i) {
            const int m = m0 + wm + i * 16 + lrow;
            const float g0 = accg[i][j][0] + gb4.x, v0 = accv[i][j][0] + vb4.x;
            const float g1 = accg[i][j][1] + gb4.y, v1 = accv[i][j][1] + vb4.y;
            const float g2 = accg[i][j][2] + gb4.z, v2 = accv[i][j][2] + vb4.z;
            const float g3 = accg[i][j][3] + gb4.w, v3 = accv[i][j][3] + vb4.w;
            const float u0 = (2.0f / (1.0f + __expf(-g0)) - 1.0f) * v0;
            const float u1 = (2.0f / (1.0f + __expf(-g1)) - 1.0f) * v1;
            const float u2 = (2.0f / (1.0f + __expf(-g2)) - 1.0f) * v2;
            const float u3 = (2.0f / (1.0f + __expf(-g3)) - 1.0f) * v3;
            uint2 o;
            o.x = pack2(u0, u1);
            o.y = pack2(u2, u3);
            *(uint2*)((unsigned short*)U + (size_t)m * N + nb) = o;
        }
    }
}

// ---------------------------------------------------------------------------
// Final GEMM: out[m,n] = X[m,n] + sum_k S[m,k]*Wo[n,k] + ob[n]
// Swapped-operand epilogue -> full float4 (16B) loads/stores.
// ---------------------------------------------------------------------------
__global__ __launch_bounds__(256, 2)
void gemm_out(const __hip_bfloat16* __restrict__ A,
              const __hip_bfloat16* __restrict__ W,
              const float* __restrict__ bias,
              const float* __restrict__ X,
              float* __restrict__ C,
              int M, int N, int K)
{
    constexpr int BK = 32;
    __shared__ short As[128 * BK];
    __shared__ short Bs[128 * BK];

    const int tid  = threadIdx.x;
    const int m0   = blockIdx.x * 128;
    const int n0   = blockIdx.y * 128;
    const int wave = tid >> 6;
    const int lane = tid & 63;
    const int wm   = (wave & 1) * 64;
    const int wn   = (wave >> 1) * 64;
    const int lrow = lane & 15;
    const int kgrp = lane >> 4;

    f32x4 acc[4][4] = {};

    const int srow = tid >> 2;
    const int sc   = tid & 3;
    const __hip_bfloat16* ga0 = A + (size_t)(m0 + srow) * K + sc * 8;
    const __hip_bfloat16* gb0 = W + (size_t)(n0 + srow) * K + sc * 8;

    for (int k0 = 0; k0 < K; k0 += BK) {
        #pragma unroll
        for (int r = 0; r < 2; ++r) {
            async_copy16(&As[(r * 256 + tid) * 8], ga0 + (size_t)r * 64 * K + k0);
            async_copy16(&Bs[(r * 256 + tid) * 8], gb0 + (size_t)r * 64 * K + k0);
        }
        __builtin_amdgcn_s_waitcnt(0);
        __syncthreads();

        bf16x8 af[4], bfr[4];
        #pragma unroll
        for (int i = 0; i < 4; ++i)
            af[i] = *(const bf16x8*)&As[(wm + i * 16 + lrow) * BK + kgrp * 8];
        #pragma unroll
        for (int j = 0; j < 4; ++j)
            bfr[j] = *(const bf16x8*)&Bs[(wn + j * 16 + lrow) * BK + kgrp * 8];

        #pragma unroll
        for (int i = 0; i < 4; ++i)
            #pragma unroll
            for (int j = 0; j < 4; ++j)
                acc[i][j] = __builtin_amdgcn_mfma_f32_16x16x32_bf16(
                    bfr[j], af[i], acc[i][j], 0, 0, 0);
        __syncthreads();
    }

    #pragma unroll
    for (int j = 0; j < 4; ++j) {
        const int nb = n0 + wn + j * 16 + kgrp * 4;
        const float4 bv = *(const float4*)(bias + nb);
        #pragma unroll
        for (int i = 0; i < 4; ++i) {
            const int m = m0 + wm + i * 16 + lrow;
            const size_t idx = (size_t)m * N + nb;
            const float4 xv = *(const float4*)(X + idx);
            float4 o;
            o.x = acc[i][j][0] + bv.x + xv.x;
            o.y = acc[i][j][1] + bv.y + xv.y;
            o.z = acc[i][j][2] + bv.z + xv.z;
            o.w = acc[i][j][3] + bv.w + xv.w;
            *(float4*)(C + idx) = o;
        }
    }
}

// ---------------------------------------------------------------------------
// Scan over T, 3-phase. NC = 64 chunks of 64 timesteps.
// 128 threads/block, 8 d's/thread -> uint4 (16B) loads/stores.
// ---------------------------------------------------------------------------
#define NC 64
#define CL 64   // chunk length

__global__ __launch_bounds__(128)
void scan_partial(const __hip_bfloat16* __restrict__ U, float* __restrict__ Pk)
{
    const int c = blockIdx.x, b = blockIdx.y;
    const int d8 = threadIdx.x * 8;
    const unsigned short* p = (const unsigned short*)U +
        ((size_t)b * TT + (size_t)c * CL) * DD + d8;
    float s[8] = {};
    #pragma unroll 8
    for (int t = 0; t < CL; ++t) {
        uint4 raw = *(const uint4*)(p + (size_t)t * DD);
        unsigned int wds[4] = {raw.x, raw.y, raw.z, raw.w};
        #pragma unroll
        for (int k = 0; k < 4; ++k) {
            s[2 * k]     += bfbits2f((unsigned short)(wds[k] & 0xFFFF));
            s[2 * k + 1] += bfbits2f((unsigned short)(wds[k] >> 16));
        }
    }
    float* o = &Pk[((size_t)b * NC + c) * DD + d8];
    *(float4*)o       = make_float4(s[0], s[1], s[2], s[3]);
    *(float4*)(o + 4) = make_float4(s[4], s[5], s[6], s[7]);
}

__global__ __launch_bounds__(256)
void scan_offsets(float* __restrict__ Pk)
{
    const int col4 = ((int)blockIdx.x * 256 + (int)threadIdx.x) * 4; // 0..4092
    const int b = col4 >> 10;
    const int d = col4 & 1023;
    float r0 = 0, r1 = 0, r2 = 0, r3 = 0;
    float* p = Pk + (size_t)b * NC * DD + d;
    #pragma unroll 8
    for (int c = 0; c < NC; ++c) {
        float4 v = *(float4*)(p + (size_t)c * DD);
        *(float4*)(p + (size_t)c * DD) = make_float4(r0, r1, r2, r3);
        r0 += v.x; r1 += v.y; r2 += v.z; r3 += v.w;
    }
}

__global__ __launch_bounds__(128)
void scan_final(const __hip_bfloat16* __restrict__ U,
                const float* __restrict__ Pk,
                const float* __restrict__ log_decay,
                __hip_bfloat16* __restrict__ S)
{
    const int c = blockIdx.x, b = blockIdx.y;
    const int d8 = threadIdx.x * 8;

    const float ld = log_decay[0];
    const float alpha = log1pf(__expf(ld));          // softplus
    const float ratio = __expf(-alpha);
    float dec = __expf(-alpha * (float)(c * CL));

    const float* pk = &Pk[((size_t)b * NC + c) * DD + d8];
    float run[8];
    float4 r0 = *(const float4*)pk;
    float4 r1 = *(const float4*)(pk + 4);
    run[0] = r0.x; run[1] = r0.y; run[2] = r0.z; run[3] = r0.w;
    run[4] = r1.x; run[5] = r1.y; run[6] = r1.z; run[7] = r1.w;

    const size_t base = ((size_t)b * TT + (size_t)c * CL) * DD + d8;
    const unsigned short* up = (const unsigned short*)U + base;
    unsigned short* sp = (unsigned short*)S + base;

    #pragma unroll 8
    for (int t = 0; t < CL; ++t) {
        uint4 raw = *(const uint4*)(up + (size_t)t * DD);
        unsigned int wds[4] = {raw.x, raw.y, raw.z, raw.w};
        uint4 o;
        unsigned int* ow = (unsigned int*)&o;
        #pragma unroll
        for (int k = 0; k < 4; ++k) {
            run[2 * k]     += bfbits2f((unsigned short)(wds[k] & 0xFFFF));
            run[2 * k + 1] += bfbits2f((unsigned short)(wds[k] >> 16));
            ow[k] = pack2(run[2 * k] * dec, run[2 * k + 1] * dec);
        }
        *(uint4*)(sp + (size_t)t * DD) = o;
        dec *= ratio;
    }
}

// ---------------------------------------------------------------------------
// Workspace: 39 MB. normed/S 32 MB | Pk 1 MB | Wg/Wv/Wo bf16 2 MB each.
// U (bf16, 32 MB) lives in d_out (fp32 64 MB); dead before gemm_out writes.
// ---------------------------------------------------------------------------
extern "C" void kernel_launch(void* const* d_in, const int* in_sizes, int n_in,
                              void* d_out, int out_size, void* d_ws, size_t ws_size,
                              hipStream_t stream)
{
    const float* x        = (const float*)d_in[0];
    const float* ln_w     = (const float*)d_in[1];
    const float* ln_b     = (const float*)d_in[2];
    const float* gate_w   = (const float*)d_in[3];
    const float* gate_b   = (const float*)d_in[4];
    const float* value_w  = (const float*)d_in[5];
    const float* value_b  = (const float*)d_in[6];
    const float* out_w    = (const float*)d_in[7];
    const float* out_b    = (const float*)d_in[8];
    const float* log_dec  = (const float*)d_in[9];
    float* out = (float*)d_out;

    char* ws = (char*)d_ws;
    const size_t MB = 1024 * 1024;
    __hip_bfloat16* normed = (__hip_bfloat16*)(ws);           // 32 MB, reused as S
    __hip_bfloat16* S      = (__hip_bfloat16*)(ws);
    float*          Pk     = (float*)(ws + 32 * MB);          // 1 MB
    __hip_bfloat16* Wg16   = (__hip_bfloat16*)(ws + 33 * MB); // 2 MB
    __hip_bfloat16* Wv16   = (__hip_bfloat16*)(ws + 35 * MB); // 2 MB
    __hip_bfloat16* Wo16   = (__hip_bfloat16*)(ws + 37 * MB); // 2 MB
    __hip_bfloat16* U      = (__hip_bfloat16*)d_out;          // scratch in d_out

    // 0. weight conversion fp32 -> bf16 (single launch)
    convert_w3<<<dim3(3072), dim3(256), 0, stream>>>(
        gate_w, value_w, out_w, Wg16, Wv16, Wo16);

    // 1. LayerNorm: x -> normed (bf16), wave-per-row
    ln_kernel<<<dim3(MM / 4), dim3(256), 0, stream>>>(x, ln_w, ln_b, normed);

    // 2. fused gate+value projections + gating: normed -> U (in d_out)
    dual_gemm_gate<<<dim3(MM / 128, DD / 128), dim3(256), 0, stream>>>(
        normed, Wg16, Wv16, gate_b, value_b, U, MM, DD, DD);

    // 3. decay-weighted cumsum over T: U -> S (overwrites normed; it's dead)
    scan_partial<<<dim3(NC, BB), dim3(128), 0, stream>>>(U, Pk);
    scan_offsets<<<dim3(4), dim3(256), 0, stream>>>(Pk);
    scan_final<<<dim3(NC, BB), dim3(128), 0, stream>>>(U, Pk, log_dec, S);

    // 4. out = x + S @ out_w^T + out_b   (overwrites U; it's dead)
    gemm_out<<<dim3(MM / 128, DD / 128), dim3(256), 0, stream>>>(
        S, Wo16, out_b, x, out, MM, DD, DD);
}

// Round 5
// 297.254 us; speedup vs baseline: 1.0751x; 1.0751x over previous
//
#include <hip/hip_runtime.h>
#include <hip/hip_bf16.h>

// Problem constants (B=4, T=4096, D=1024). FP32 I/O, bf16 MFMA internally.
#define BB 4
#define TT 4096
#define DD 1024
#define MM (BB * TT)   // 16384 rows
#define LN_EPS 1e-5f

typedef __attribute__((ext_vector_type(8))) short bf16x8;   // 8 bf16 = 4 VGPRs
typedef __attribute__((ext_vector_type(4))) float f32x4;

__device__ __forceinline__ float bfbits2f(unsigned short h) {
    return __uint_as_float(((unsigned int)h) << 16);
}
__device__ __forceinline__ unsigned short f2bfbits(float f) {
    __hip_bfloat16 h = __float2bfloat16(f);
    return *reinterpret_cast<unsigned short*>(&h);
}
__device__ __forceinline__ unsigned int pack2(float a, float b) {
    return (unsigned int)f2bfbits(a) | ((unsigned int)f2bfbits(b) << 16);
}

// async global->LDS, 16B per lane (wave-uniform LDS base + lane*16).
__device__ __forceinline__ void async_copy16(void* lds, const void* g) {
    __builtin_amdgcn_global_load_lds(
        (const __attribute__((address_space(1))) void*)g,
        (__attribute__((address_space(3))) void*)lds,
        16, 0, 0);
}

// ---------------------------------------------------------------------------
// fp32 -> bf16 conversion of the 3 weight matrices in ONE launch.
// ---------------------------------------------------------------------------
__global__ __launch_bounds__(256)
void convert_w3(const float* __restrict__ s0, const float* __restrict__ s1,
                const float* __restrict__ s2,
                __hip_bfloat16* __restrict__ d0, __hip_bfloat16* __restrict__ d1,
                __hip_bfloat16* __restrict__ d2)
{
    const int blk = blockIdx.x;
    const int w = blk >> 10;
    const float* src = (w == 0) ? s0 : (w == 1) ? s1 : s2;
    __hip_bfloat16* dst = (w == 0) ? d0 : (w == 1) ? d1 : d2;
    const size_t i = ((size_t)(blk & 1023) * 256 + threadIdx.x) * 4;
    float4 v = *(const float4*)(src + i);
    uint2 o;
    o.x = pack2(v.x, v.y);
    o.y = pack2(v.z, v.w);
    *(uint2*)((unsigned short*)dst + i) = o;
}

// ---------------------------------------------------------------------------
// LayerNorm: fp32 in -> bf16 out. One WAVE per row (4 rows / 256-thr block).
// ---------------------------------------------------------------------------
__global__ __launch_bounds__(256)
void ln_kernel(const float* __restrict__ x,
               const float* __restrict__ w,
               const float* __restrict__ b,
               __hip_bfloat16* __restrict__ out)
{
    const int wv   = threadIdx.x >> 6;
    const int lane = threadIdx.x & 63;
    const int row  = blockIdx.x * 4 + wv;

    const float* xr = x + (size_t)row * DD + lane * 16;
    float4 v[4];
    #pragma unroll
    for (int i = 0; i < 4; ++i) v[i] = *(const float4*)(xr + i * 4);

    float s = 0.0f, ss = 0.0f;
    #pragma unroll
    for (int i = 0; i < 4; ++i) {
        s  += (v[i].x + v[i].y) + (v[i].z + v[i].w);
        ss += fmaf(v[i].x, v[i].x, fmaf(v[i].y, v[i].y,
              fmaf(v[i].z, v[i].z, v[i].w * v[i].w)));
    }
    #pragma unroll
    for (int o = 32; o > 0; o >>= 1) {
        s  += __shfl_down(s, o);
        ss += __shfl_down(ss, o);
    }
    s  = __shfl(s, 0);
    ss = __shfl(ss, 0);

    const float mu   = s * (1.0f / DD);
    const float var  = ss * (1.0f / DD) - mu * mu;
    const float rstd = rsqrtf(var + LN_EPS);

    unsigned int res[8];
    #pragma unroll
    for (int i = 0; i < 4; ++i) {
        float4 wr = *(const float4*)(w + lane * 16 + i * 4);
        float4 br = *(const float4*)(b + lane * 16 + i * 4);
        float o0 = (v[i].x - mu) * rstd * wr.x + br.x;
        float o1 = (v[i].y - mu) * rstd * wr.y + br.y;
        float o2 = (v[i].z - mu) * rstd * wr.z + br.z;
        float o3 = (v[i].w - mu) * rstd * wr.w + br.w;
        res[i * 2]     = pack2(o0, o1);
        res[i * 2 + 1] = pack2(o2, o3);
    }
    unsigned short* op = (unsigned short*)out + (size_t)row * DD + lane * 16;
    *(uint4*)op       = make_uint4(res[0], res[1], res[2], res[3]);
    *(uint4*)(op + 8) = make_uint4(res[4], res[5], res[6], res[7]);
}

// ---------------------------------------------------------------------------
// Fused dual GEMM + gate, BK=64 + XOR bank swizzle.
//   g = A @ Wg^T + gb;  v = A @ Wv^T + vb;  U = (2*sigmoid(g)-1)*v
// LDS rows are 128B (64 bf16). 16B chunk cc of row r is stored at chunk
// slot cc ^ (r&7): spreads the 16 lrow-lanes of a fragment read across
// 8 distinct 4-bank groups (8 lanes/bank = wave64-b128 floor).
// Swizzle is applied on the *source address* of global_load_lds (LDS side
// must remain lane-linear), and re-applied on ds_read.
// Epilogue operand-swap (round 4, verified): m=lane&15, n=kgrp*4+reg.
// ---------------------------------------------------------------------------
__global__ __launch_bounds__(256, 2)
void dual_gemm_gate(const __hip_bfloat16* __restrict__ A,
                    const __hip_bfloat16* __restrict__ Wg,
                    const __hip_bfloat16* __restrict__ Wv,
                    const float* __restrict__ gb,
                    const float* __restrict__ vb,
                    __hip_bfloat16* __restrict__ U,
                    int M, int N, int K)
{
    constexpr int BK = 64;
    __shared__ short As[128 * BK];   // 16 KB each
    __shared__ short Bg[128 * BK];
    __shared__ short Bv[128 * BK];

    const int tid  = threadIdx.x;
    const int m0   = blockIdx.x * 128;
    const int n0   = blockIdx.y * 128;
    const int wave = tid >> 6;
    const int lane = tid & 63;
    const int wm   = (wave & 1) * 64;
    const int wn   = (wave >> 1) * 64;
    const int lrow = lane & 15;
    const int kgrp = lane >> 4;      // 0..3
    const int swz  = lrow & 7;       // read-side swizzle key

    f32x4 accg[4][4] = {};
    f32x4 accv[4][4] = {};

    // staging: slot = r*256+tid -> row = slot>>3 (0..127), chunk = slot&7.
    // lane fetches global chunk (slot&7) ^ (row&7)  [XOR self-inverse]
    const __hip_bfloat16* gA[4];
    const __hip_bfloat16* gG[4];
    const __hip_bfloat16* gV[4];
    #pragma unroll
    for (int r = 0; r < 4; ++r) {
        const int slot = r * 256 + tid;
        const int srow = slot >> 3;
        const int gcc  = (slot & 7) ^ (srow & 7);
        gA[r] = A  + (size_t)(m0 + srow) * K + gcc * 8;
        gG[r] = Wg + (size_t)(n0 + srow) * K + gcc * 8;
        gV[r] = Wv + (size_t)(n0 + srow) * K + gcc * 8;
    }

    for (int k0 = 0; k0 < K; k0 += BK) {
        #pragma unroll
        for (int r = 0; r < 4; ++r) {
            async_copy16(&As[(r * 256 + tid) * 8], gA[r] + k0);
            async_copy16(&Bg[(r * 256 + tid) * 8], gG[r] + k0);
            async_copy16(&Bv[(r * 256 + tid) * 8], gV[r] + k0);
        }
        __builtin_amdgcn_s_waitcnt(0);
        __syncthreads();

        #pragma unroll
        for (int ks = 0; ks < 2; ++ks) {
            const int co = ((ks * 4 + kgrp) ^ swz) * 8;   // swizzled chunk offset
            bf16x8 af[4], bgf[4], bvf[4];
            #pragma unroll
            for (int i = 0; i < 4; ++i)
                af[i] = *(const bf16x8*)&As[(wm + i * 16 + lrow) * BK + co];
            #pragma unroll
            for (int j = 0; j < 4; ++j) {
                bgf[j] = *(const bf16x8*)&Bg[(wn + j * 16 + lrow) * BK + co];
                bvf[j] = *(const bf16x8*)&Bv[(wn + j * 16 + lrow) * BK + co];
            }
            #pragma unroll
            for (int i = 0; i < 4; ++i)
                #pragma unroll
                for (int j = 0; j < 4; ++j) {
                    accg[i][j] = __builtin_amdgcn_mfma_f32_16x16x32_bf16(
                        bgf[j], af[i], accg[i][j], 0, 0, 0);
                    accv[i][j] = __builtin_amdgcn_mfma_f32_16x16x32_bf16(
                        bvf[j], af[i], accv[i][j], 0, 0, 0);
                }
        }
        __syncthreads();
    }

    #pragma unroll
    for (int j = 0; j < 4; ++j) {
        const int nb = n0 + wn + j * 16 + kgrp * 4;
        const float4 gb4 = *(const float4*)(gb + nb);
        const float4 vb4 = *(const float4*)(vb + nb);
        #pragma unroll
        for (int i = 0; i < 4; ++i) {
            const int m = m0 + wm + i * 16 + lrow;
            const float g0 = accg[i][j][0] + gb4.x, v0 = accv[i][j][0] + vb4.x;
            const float g1 = accg[i][j][1] + gb4.y, v1 = accv[i][j][1] + vb4.y;
            const float g2 = accg[i][j][2] + gb4.z, v2 = accv[i][j][2] + vb4.z;
            const float g3 = accg[i][j][3] + gb4.w, v3 = accv[i][j][3] + vb4.w;
            const float u0 = (2.0f / (1.0f + __expf(-g0)) - 1.0f) * v0;
            const float u1 = (2.0f / (1.0f + __expf(-g1)) - 1.0f) * v1;
            const float u2 = (2.0f / (1.0f + __expf(-g2)) - 1.0f) * v2;
            const float u3 = (2.0f / (1.0f + __expf(-g3)) - 1.0f) * v3;
            uint2 o;
            o.x = pack2(u0, u1);
            o.y = pack2(u2, u3);
            *(uint2*)((unsigned short*)U + (size_t)m * N + nb) = o;
        }
    }
}

// ---------------------------------------------------------------------------
// Final GEMM: out[m,n] = X[m,n] + sum_k S[m,k]*Wo[n,k] + ob[n]
// BK=64 + swizzle; swapped-operand epilogue, float4 loads/stores.
// ---------------------------------------------------------------------------
__global__ __launch_bounds__(256, 2)
void gemm_out(const __hip_bfloat16* __restrict__ A,
              const __hip_bfloat16* __restrict__ W,
              const float* __restrict__ bias,
              const float* __restrict__ X,
              float* __restrict__ C,
              int M, int N, int K)
{
    constexpr int BK = 64;
    __shared__ short As[128 * BK];
    __shared__ short Bs[128 * BK];

    const int tid  = threadIdx.x;
    const int m0   = blockIdx.x * 128;
    const int n0   = blockIdx.y * 128;
    const int wave = tid >> 6;
    const int lane = tid & 63;
    const int wm   = (wave & 1) * 64;
    const int wn   = (wave >> 1) * 64;
    const int lrow = lane & 15;
    const int kgrp = lane >> 4;
    const int swz  = lrow & 7;

    f32x4 acc[4][4] = {};

    const __hip_bfloat16* gA[4];
    const __hip_bfloat16* gB[4];
    #pragma unroll
    for (int r = 0; r < 4; ++r) {
        const int slot = r * 256 + tid;
        const int srow = slot >> 3;
        const int gcc  = (slot & 7) ^ (srow & 7);
        gA[r] = A + (size_t)(m0 + srow) * K + gcc * 8;
        gB[r] = W + (size_t)(n0 + srow) * K + gcc * 8;
    }

    for (int k0 = 0; k0 < K; k0 += BK) {
        #pragma unroll
        for (int r = 0; r < 4; ++r) {
            async_copy16(&As[(r * 256 + tid) * 8], gA[r] + k0);
            async_copy16(&Bs[(r * 256 + tid) * 8], gB[r] + k0);
        }
        __builtin_amdgcn_s_waitcnt(0);
        __syncthreads();

        #pragma unroll
        for (int ks = 0; ks < 2; ++ks) {
            const int co = ((ks * 4 + kgrp) ^ swz) * 8;
            bf16x8 af[4], bfr[4];
            #pragma unroll
            for (int i = 0; i < 4; ++i)
                af[i] = *(const bf16x8*)&As[(wm + i * 16 + lrow) * BK + co];
            #pragma unroll
            for (int j = 0; j < 4; ++j)
                bfr[j] = *(const bf16x8*)&Bs[(wn + j * 16 + lrow) * BK + co];
            #pragma unroll
            for (int i = 0; i < 4; ++i)
                #pragma unroll
                for (int j = 0; j < 4; ++j)
                    acc[i][j] = __builtin_amdgcn_mfma_f32_16x16x32_bf16(
                        bfr[j], af[i], acc[i][j], 0, 0, 0);
        }
        __syncthreads();
    }

    #pragma unroll
    for (int j = 0; j < 4; ++j) {
        const int nb = n0 + wn + j * 16 + kgrp * 4;
        const float4 bv = *(const float4*)(bias + nb);
        #pragma unroll
        for (int i = 0; i < 4; ++i) {
            const int m = m0 + wm + i * 16 + lrow;
            const size_t idx = (size_t)m * N + nb;
            const float4 xv = *(const float4*)(X + idx);
            float4 o;
            o.x = acc[i][j][0] + bv.x + xv.x;
            o.y = acc[i][j][1] + bv.y + xv.y;
            o.z = acc[i][j][2] + bv.z + xv.z;
            o.w = acc[i][j][3] + bv.w + xv.w;
            *(float4*)(C + idx) = o;
        }
    }
}

// ---------------------------------------------------------------------------
// Scan over T, 3-phase. NC = 64 chunks of 64 timesteps.
// ---------------------------------------------------------------------------
#define NC 64
#define CL 64   // chunk length

__global__ __launch_bounds__(128)
void scan_partial(const __hip_bfloat16* __restrict__ U, float* __restrict__ Pk)
{
    const int c = blockIdx.x, b = blockIdx.y;
    const int d8 = threadIdx.x * 8;
    const unsigned short* p = (const unsigned short*)U +
        ((size_t)b * TT + (size_t)c * CL) * DD + d8;
    float s[8] = {};
    #pragma unroll 8
    for (int t = 0; t < CL; ++t) {
        uint4 raw = *(const uint4*)(p + (size_t)t * DD);
        unsigned int wds[4] = {raw.x, raw.y, raw.z, raw.w};
        #pragma unroll
        for (int k = 0; k < 4; ++k) {
            s[2 * k]     += bfbits2f((unsigned short)(wds[k] & 0xFFFF));
            s[2 * k + 1] += bfbits2f((unsigned short)(wds[k] >> 16));
        }
    }
    float* o = &Pk[((size_t)b * NC + c) * DD + d8];
    *(float4*)o       = make_float4(s[0], s[1], s[2], s[3]);
    *(float4*)(o + 4) = make_float4(s[4], s[5], s[6], s[7]);
}

__global__ __launch_bounds__(256)
void scan_offsets(float* __restrict__ Pk)
{
    const int col4 = ((int)blockIdx.x * 256 + (int)threadIdx.x) * 4; // 0..4092
    const int b = col4 >> 10;
    const int d = col4 & 1023;
    float r0 = 0, r1 = 0, r2 = 0, r3 = 0;
    float* p = Pk + (size_t)b * NC * DD + d;
    #pragma unroll 8
    for (int c = 0; c < NC; ++c) {
        float4 v = *(float4*)(p + (size_t)c * DD);
        *(float4*)(p + (size_t)c * DD) = make_float4(r0, r1, r2, r3);
        r0 += v.x; r1 += v.y; r2 += v.z; r3 += v.w;
    }
}

__global__ __launch_bounds__(128)
void scan_final(const __hip_bfloat16* __restrict__ U,
                const float* __restrict__ Pk,
                const float* __restrict__ log_decay,
                __hip_bfloat16* __restrict__ S)
{
    const int c = blockIdx.x, b = blockIdx.y;
    const int d8 = threadIdx.x * 8;

    const float ld = log_decay[0];
    const float alpha = log1pf(__expf(ld));          // softplus
    const float ratio = __expf(-alpha);
    float dec = __expf(-alpha * (float)(c * CL));

    const float* pk = &Pk[((size_t)b * NC + c) * DD + d8];
    float run[8];
    float4 r0 = *(const float4*)pk;
    float4 r1 = *(const float4*)(pk + 4);
    run[0] = r0.x; run[1] = r0.y; run[2] = r0.z; run[3] = r0.w;
    run[4] = r1.x; run[5] = r1.y; run[6] = r1.z; run[7] = r1.w;

    const size_t base = ((size_t)b * TT + (size_t)c * CL) * DD + d8;
    const unsigned short* up = (const unsigned short*)U + base;
    unsigned short* sp = (unsigned short*)S + base;

    #pragma unroll 8
    for (int t = 0; t < CL; ++t) {
        uint4 raw = *(const uint4*)(up + (size_t)t * DD);
        unsigned int wds[4] = {raw.x, raw.y, raw.z, raw.w};
        uint4 o;
        unsigned int* ow = (unsigned int*)&o;
        #pragma unroll
        for (int k = 0; k < 4; ++k) {
            run[2 * k]     += bfbits2f((unsigned short)(wds[k] & 0xFFFF));
            run[2 * k + 1] += bfbits2f((unsigned short)(wds[k] >> 16));
            ow[k] = pack2(run[2 * k] * dec, run[2 * k + 1] * dec);
        }
        *(uint4*)(sp + (size_t)t * DD) = o;
        dec *= ratio;
    }
}

// ---------------------------------------------------------------------------
// Workspace: 39 MB. normed/S 32 MB | Pk 1 MB | Wg/Wv/Wo bf16 2 MB each.
// U (bf16, 32 MB) lives in d_out (fp32 64 MB); dead before gemm_out writes.
// ---------------------------------------------------------------------------
extern "C" void kernel_launch(void* const* d_in, const int* in_sizes, int n_in,
                              void* d_out, int out_size, void* d_ws, size_t ws_size,
                              hipStream_t stream)
{
    const float* x        = (const float*)d_in[0];
    const float* ln_w     = (const float*)d_in[1];
    const float* ln_b     = (const float*)d_in[2];
    const float* gate_w   = (const float*)d_in[3];
    const float* gate_b   = (const float*)d_in[4];
    const float* value_w  = (const float*)d_in[5];
    const float* value_b  = (const float*)d_in[6];
    const float* out_w    = (const float*)d_in[7];
    const float* out_b    = (const float*)d_in[8];
    const float* log_dec  = (const float*)d_in[9];
    float* out = (float*)d_out;

    char* ws = (char*)d_ws;
    const size_t MB = 1024 * 1024;
    __hip_bfloat16* normed = (__hip_bfloat16*)(ws);           // 32 MB, reused as S
    __hip_bfloat16* S      = (__hip_bfloat16*)(ws);
    float*          Pk     = (float*)(ws + 32 * MB);          // 1 MB
    __hip_bfloat16* Wg16   = (__hip_bfloat16*)(ws + 33 * MB); // 2 MB
    __hip_bfloat16* Wv16   = (__hip_bfloat16*)(ws + 35 * MB); // 2 MB
    __hip_bfloat16* Wo16   = (__hip_bfloat16*)(ws + 37 * MB); // 2 MB
    __hip_bfloat16* U      = (__hip_bfloat16*)d_out;          // scratch in d_out

    // 0. weight conversion fp32 -> bf16 (single launch)
    convert_w3<<<dim3(3072), dim3(256), 0, stream>>>(
        gate_w, value_w, out_w, Wg16, Wv16, Wo16);

    // 1. LayerNorm: x -> normed (bf16), wave-per-row
    ln_kernel<<<dim3(MM / 4), dim3(256), 0, stream>>>(x, ln_w, ln_b, normed);

    // 2. fused gate+value projections + gating: normed -> U (in d_out)
    dual_gemm_gate<<<dim3(MM / 128, DD / 128), dim3(256), 0, stream>>>(
        normed, Wg16, Wv16, gate_b, value_b, U, MM, DD, DD);

    // 3. decay-weighted cumsum over T: U -> S (overwrites normed; it's dead)
    scan_partial<<<dim3(NC, BB), dim3(128), 0, stream>>>(U, Pk);
    scan_offsets<<<dim3(4), dim3(256), 0, stream>>>(Pk);
    scan_final<<<dim3(NC, BB), dim3(128), 0, stream>>>(U, Pk, log_dec, S);

    // 4. out = x + S @ out_w^T + out_b   (overwrites U; it's dead)
    gemm_out<<<dim3(MM / 128, DD / 128), dim3(256), 0, stream>>>(
        S, Wo16, out_b, x, out, MM, DD, DD);
}

// Round 6
// 292.775 us; speedup vs baseline: 1.0916x; 1.0153x over previous
//
#include <hip/hip_runtime.h>
#include <hip/hip_bf16.h>

// Problem constants (B=4, T=4096, D=1024). FP32 I/O, bf16 MFMA internally.
#define BB 4
#define TT 4096
#define DD 1024
#define MM (BB * TT)   // 16384 rows
#define LN_EPS 1e-5f

#define NC 64
#define CL 64   // chunk length

typedef __attribute__((ext_vector_type(8))) short bf16x8;   // 8 bf16 = 4 VGPRs
typedef __attribute__((ext_vector_type(4))) float f32x4;

__device__ __forceinline__ float bfbits2f(unsigned short h) {
    return __uint_as_float(((unsigned int)h) << 16);
}
__device__ __forceinline__ unsigned short f2bfbits(float f) {
    __hip_bfloat16 h = __float2bfloat16(f);
    return *reinterpret_cast<unsigned short*>(&h);
}
__device__ __forceinline__ unsigned int pack2(float a, float b) {
    return (unsigned int)f2bfbits(a) | ((unsigned int)f2bfbits(b) << 16);
}

// async global->LDS, 16B per lane (wave-uniform LDS base + lane*16).
__device__ __forceinline__ void async_copy16(void* lds, const void* g) {
    __builtin_amdgcn_global_load_lds(
        (const __attribute__((address_space(1))) void*)g,
        (__attribute__((address_space(3))) void*)lds,
        16, 0, 0);
}

// ---------------------------------------------------------------------------
// fp32 -> bf16 conversion of the 3 weight matrices in ONE launch.
// ---------------------------------------------------------------------------
__global__ __launch_bounds__(256)
void convert_w3(const float* __restrict__ s0, const float* __restrict__ s1,
                const float* __restrict__ s2,
                __hip_bfloat16* __restrict__ d0, __hip_bfloat16* __restrict__ d1,
                __hip_bfloat16* __restrict__ d2)
{
    const int blk = blockIdx.x;
    const int w = blk >> 10;
    const float* src = (w == 0) ? s0 : (w == 1) ? s1 : s2;
    __hip_bfloat16* dst = (w == 0) ? d0 : (w == 1) ? d1 : d2;
    const size_t i = ((size_t)(blk & 1023) * 256 + threadIdx.x) * 4;
    float4 v = *(const float4*)(src + i);
    uint2 o;
    o.x = pack2(v.x, v.y);
    o.y = pack2(v.z, v.w);
    *(uint2*)((unsigned short*)dst + i) = o;
}

// ---------------------------------------------------------------------------
// LayerNorm: fp32 in -> bf16 out. One WAVE per row (4 rows / 256-thr block).
// ---------------------------------------------------------------------------
__global__ __launch_bounds__(256)
void ln_kernel(const float* __restrict__ x,
               const float* __restrict__ w,
               const float* __restrict__ b,
               __hip_bfloat16* __restrict__ out)
{
    const int wv   = threadIdx.x >> 6;
    const int lane = threadIdx.x & 63;
    const int row  = blockIdx.x * 4 + wv;

    const float* xr = x + (size_t)row * DD + lane * 16;
    float4 v[4];
    #pragma unroll
    for (int i = 0; i < 4; ++i) v[i] = *(const float4*)(xr + i * 4);

    float s = 0.0f, ss = 0.0f;
    #pragma unroll
    for (int i = 0; i < 4; ++i) {
        s  += (v[i].x + v[i].y) + (v[i].z + v[i].w);
        ss += fmaf(v[i].x, v[i].x, fmaf(v[i].y, v[i].y,
              fmaf(v[i].z, v[i].z, v[i].w * v[i].w)));
    }
    #pragma unroll
    for (int o = 32; o > 0; o >>= 1) {
        s  += __shfl_down(s, o);
        ss += __shfl_down(ss, o);
    }
    s  = __shfl(s, 0);
    ss = __shfl(ss, 0);

    const float mu   = s * (1.0f / DD);
    const float var  = ss * (1.0f / DD) - mu * mu;
    const float rstd = rsqrtf(var + LN_EPS);

    unsigned int res[8];
    #pragma unroll
    for (int i = 0; i < 4; ++i) {
        float4 wr = *(const float4*)(w + lane * 16 + i * 4);
        float4 br = *(const float4*)(b + lane * 16 + i * 4);
        float o0 = (v[i].x - mu) * rstd * wr.x + br.x;
        float o1 = (v[i].y - mu) * rstd * wr.y + br.y;
        float o2 = (v[i].z - mu) * rstd * wr.z + br.z;
        float o3 = (v[i].w - mu) * rstd * wr.w + br.w;
        res[i * 2]     = pack2(o0, o1);
        res[i * 2 + 1] = pack2(o2, o3);
    }
    unsigned short* op = (unsigned short*)out + (size_t)row * DD + lane * 16;
    *(uint4*)op       = make_uint4(res[0], res[1], res[2], res[3]);
    *(uint4*)(op + 8) = make_uint4(res[4], res[5], res[6], res[7]);
}

// ---------------------------------------------------------------------------
// Fused dual GEMM + gate + CHUNK-SUM epilogue.
//   g = A @ Wg^T + gb;  v = A @ Wv^T + vb;  U = (2*sigmoid(g)-1)*v
//   Pk[b, chunk, n] = sum over the wave's 64 m-rows of u  (each (chunk,n)
//   is produced by exactly one wave: wm picks the chunk, wn/n0 pick n).
// BK=64 + XOR bank swizzle (round 5, verified conflict-free).
// Operand-swap epilogue: m = lane&15, n = kgrp*4 + reg.
// ---------------------------------------------------------------------------
__global__ __launch_bounds__(256, 2)
void dual_gemm_gate(const __hip_bfloat16* __restrict__ A,
                    const __hip_bfloat16* __restrict__ Wg,
                    const __hip_bfloat16* __restrict__ Wv,
                    const float* __restrict__ gb,
                    const float* __restrict__ vb,
                    __hip_bfloat16* __restrict__ U,
                    float* __restrict__ Pk,
                    int M, int N, int K)
{
    constexpr int BK = 64;
    __shared__ short As[128 * BK];   // 16 KB each
    __shared__ short Bg[128 * BK];
    __shared__ short Bv[128 * BK];

    const int tid  = threadIdx.x;
    const int m0   = blockIdx.x * 128;
    const int n0   = blockIdx.y * 128;
    const int wave = tid >> 6;
    const int lane = tid & 63;
    const int wm   = (wave & 1) * 64;
    const int wn   = (wave >> 1) * 64;
    const int lrow = lane & 15;
    const int kgrp = lane >> 4;      // 0..3
    const int swz  = lrow & 7;       // read-side swizzle key

    f32x4 accg[4][4] = {};
    f32x4 accv[4][4] = {};

    // staging: slot = r*256+tid -> row = slot>>3 (0..127), chunk = slot&7.
    // lane fetches global chunk (slot&7) ^ (row&7)  [XOR self-inverse]
    const __hip_bfloat16* gA[4];
    const __hip_bfloat16* gG[4];
    const __hip_bfloat16* gV[4];
    #pragma unroll
    for (int r = 0; r < 4; ++r) {
        const int slot = r * 256 + tid;
        const int srow = slot >> 3;
        const int gcc  = (slot & 7) ^ (srow & 7);
        gA[r] = A  + (size_t)(m0 + srow) * K + gcc * 8;
        gG[r] = Wg + (size_t)(n0 + srow) * K + gcc * 8;
        gV[r] = Wv + (size_t)(n0 + srow) * K + gcc * 8;
    }

    for (int k0 = 0; k0 < K; k0 += BK) {
        #pragma unroll
        for (int r = 0; r < 4; ++r) {
            async_copy16(&As[(r * 256 + tid) * 8], gA[r] + k0);
            async_copy16(&Bg[(r * 256 + tid) * 8], gG[r] + k0);
            async_copy16(&Bv[(r * 256 + tid) * 8], gV[r] + k0);
        }
        __builtin_amdgcn_s_waitcnt(0);
        __syncthreads();

        #pragma unroll
        for (int ks = 0; ks < 2; ++ks) {
            const int co = ((ks * 4 + kgrp) ^ swz) * 8;   // swizzled chunk offset
            bf16x8 af[4], bgf[4], bvf[4];
            #pragma unroll
            for (int i = 0; i < 4; ++i)
                af[i] = *(const bf16x8*)&As[(wm + i * 16 + lrow) * BK + co];
            #pragma unroll
            for (int j = 0; j < 4; ++j) {
                bgf[j] = *(const bf16x8*)&Bg[(wn + j * 16 + lrow) * BK + co];
                bvf[j] = *(const bf16x8*)&Bv[(wn + j * 16 + lrow) * BK + co];
            }
            #pragma unroll
            for (int i = 0; i < 4; ++i)
                #pragma unroll
                for (int j = 0; j < 4; ++j) {
                    accg[i][j] = __builtin_amdgcn_mfma_f32_16x16x32_bf16(
                        bgf[j], af[i], accg[i][j], 0, 0, 0);
                    accv[i][j] = __builtin_amdgcn_mfma_f32_16x16x32_bf16(
                        bvf[j], af[i], accv[i][j], 0, 0, 0);
                }
        }
        __syncthreads();
    }

    // chunk id for this wave's 64 m-rows
    const int chrow = m0 + wm;
    const int cb    = chrow >> 12;            // / TT
    const int cc    = (chrow & (TT - 1)) >> 6; // chunk within batch

    #pragma unroll
    for (int j = 0; j < 4; ++j) {
        const int nb = n0 + wn + j * 16 + kgrp * 4;
        const float4 gb4 = *(const float4*)(gb + nb);
        const float4 vb4 = *(const float4*)(vb + nb);
        float4 ps = make_float4(0.f, 0.f, 0.f, 0.f);
        #pragma unroll
        for (int i = 0; i < 4; ++i) {
            const int m = m0 + wm + i * 16 + lrow;
            const float g0 = accg[i][j][0] + gb4.x, v0 = accv[i][j][0] + vb4.x;
            const float g1 = accg[i][j][1] + gb4.y, v1 = accv[i][j][1] + vb4.y;
            const float g2 = accg[i][j][2] + gb4.z, v2 = accv[i][j][2] + vb4.z;
            const float g3 = accg[i][j][3] + gb4.w, v3 = accv[i][j][3] + vb4.w;
            const float u0 = (2.0f / (1.0f + __expf(-g0)) - 1.0f) * v0;
            const float u1 = (2.0f / (1.0f + __expf(-g1)) - 1.0f) * v1;
            const float u2 = (2.0f / (1.0f + __expf(-g2)) - 1.0f) * v2;
            const float u3 = (2.0f / (1.0f + __expf(-g3)) - 1.0f) * v3;
            ps.x += u0; ps.y += u1; ps.z += u2; ps.w += u3;
            uint2 o;
            o.x = pack2(u0, u1);
            o.y = pack2(u2, u3);
            *(uint2*)((unsigned short*)U + (size_t)m * N + nb) = o;
        }
        // reduce across the 16 lrow-lanes of this kgrp group
        #pragma unroll
        for (int mk = 1; mk <= 8; mk <<= 1) {
            ps.x += __shfl_xor(ps.x, mk);
            ps.y += __shfl_xor(ps.y, mk);
            ps.z += __shfl_xor(ps.z, mk);
            ps.w += __shfl_xor(ps.w, mk);
        }
        if (lrow == 0)
            *(float4*)&Pk[((size_t)cb * NC + cc) * DD + nb] = ps;
    }
}

// ---------------------------------------------------------------------------
// Final GEMM: out[m,n] = X[m,n] + sum_k S[m,k]*Wo[n,k] + ob[n]
// BK=64 + swizzle; swapped-operand epilogue, float4 loads/stores.
// ---------------------------------------------------------------------------
__global__ __launch_bounds__(256, 2)
void gemm_out(const __hip_bfloat16* __restrict__ A,
              const __hip_bfloat16* __restrict__ W,
              const float* __restrict__ bias,
              const float* __restrict__ X,
              float* __restrict__ C,
              int M, int N, int K)
{
    constexpr int BK = 64;
    __shared__ short As[128 * BK];
    __shared__ short Bs[128 * BK];

    const int tid  = threadIdx.x;
    const int m0   = blockIdx.x * 128;
    const int n0   = blockIdx.y * 128;
    const int wave = tid >> 6;
    const int lane = tid & 63;
    const int wm   = (wave & 1) * 64;
    const int wn   = (wave >> 1) * 64;
    const int lrow = lane & 15;
    const int kgrp = lane >> 4;
    const int swz  = lrow & 7;

    f32x4 acc[4][4] = {};

    const __hip_bfloat16* gA[4];
    const __hip_bfloat16* gB[4];
    #pragma unroll
    for (int r = 0; r < 4; ++r) {
        const int slot = r * 256 + tid;
        const int srow = slot >> 3;
        const int gcc  = (slot & 7) ^ (srow & 7);
        gA[r] = A + (size_t)(m0 + srow) * K + gcc * 8;
        gB[r] = W + (size_t)(n0 + srow) * K + gcc * 8;
    }

    for (int k0 = 0; k0 < K; k0 += BK) {
        #pragma unroll
        for (int r = 0; r < 4; ++r) {
            async_copy16(&As[(r * 256 + tid) * 8], gA[r] + k0);
            async_copy16(&Bs[(r * 256 + tid) * 8], gB[r] + k0);
        }
        __builtin_amdgcn_s_waitcnt(0);
        __syncthreads();

        #pragma unroll
        for (int ks = 0; ks < 2; ++ks) {
            const int co = ((ks * 4 + kgrp) ^ swz) * 8;
            bf16x8 af[4], bfr[4];
            #pragma unroll
            for (int i = 0; i < 4; ++i)
                af[i] = *(const bf16x8*)&As[(wm + i * 16 + lrow) * BK + co];
            #pragma unroll
            for (int j = 0; j < 4; ++j)
                bfr[j] = *(const bf16x8*)&Bs[(wn + j * 16 + lrow) * BK + co];
            #pragma unroll
            for (int i = 0; i < 4; ++i)
                #pragma unroll
                for (int j = 0; j < 4; ++j)
                    acc[i][j] = __builtin_amdgcn_mfma_f32_16x16x32_bf16(
                        bfr[j], af[i], acc[i][j], 0, 0, 0);
        }
        __syncthreads();
    }

    #pragma unroll
    for (int j = 0; j < 4; ++j) {
        const int nb = n0 + wn + j * 16 + kgrp * 4;
        const float4 bv = *(const float4*)(bias + nb);
        #pragma unroll
        for (int i = 0; i < 4; ++i) {
            const int m = m0 + wm + i * 16 + lrow;
            const size_t idx = (size_t)m * N + nb;
            const float4 xv = *(const float4*)(X + idx);
            float4 o;
            o.x = acc[i][j][0] + bv.x + xv.x;
            o.y = acc[i][j][1] + bv.y + xv.y;
            o.z = acc[i][j][2] + bv.z + xv.z;
            o.w = acc[i][j][3] + bv.w + xv.w;
            *(float4*)(C + idx) = o;
        }
    }
}

// ---------------------------------------------------------------------------
// Exclusive prefix over chunks, LDS-tile version. 64 blocks x 256 thr.
// Block bk: 64 columns [bk*64, bk*64+64) (one batch each since 64 | 1024),
// all 64 chunks. Coalesced float4 global I/O; segmented scan in LDS.
// ---------------------------------------------------------------------------
__global__ __launch_bounds__(256)
void scan_offsets(float* __restrict__ Pk)
{
    __shared__ float Tl[64][68];   // [chunk][col], pad 68 (272B rows, 16B-aligned)
    __shared__ float Seg[4][64];

    const int tid  = threadIdx.x;
    const int col0 = blockIdx.x * 64;
    const int b    = col0 >> 10;
    const int d0   = col0 & 1023;

    #pragma unroll
    for (int r = 0; r < 4; ++r) {
        const int idx = r * 256 + tid;
        const int c = idx >> 4, q = idx & 15;
        float4 v = *(const float4*)&Pk[((size_t)b * NC + c) * DD + d0 + q * 4];
        *(float4*)&Tl[c][q * 4] = v;
    }
    __syncthreads();

    const int j = tid & 63, seg = tid >> 6;
    float ssum = 0.0f;
    #pragma unroll
    for (int k = 0; k < 16; ++k) ssum += Tl[seg * 16 + k][j];
    Seg[seg][j] = ssum;
    __syncthreads();

    float run = 0.0f;
    for (int s = 0; s < seg; ++s) run += Seg[s][j];
    #pragma unroll
    for (int k = 0; k < 16; ++k) {
        const int c = seg * 16 + k;
        const float v = Tl[c][j];
        Tl[c][j] = run;
        run += v;
    }
    __syncthreads();

    #pragma unroll
    for (int r = 0; r < 4; ++r) {
        const int idx = r * 256 + tid;
        const int c = idx >> 4, q = idx & 15;
        *(float4*)&Pk[((size_t)b * NC + c) * DD + d0 + q * 4] =
            *(const float4*)&Tl[c][q * 4];
    }
}

// ---------------------------------------------------------------------------
// Within-chunk inclusive scan + decay -> S (bf16). grid (NC, BB) x 128 thr.
// ---------------------------------------------------------------------------
__global__ __launch_bounds__(128)
void scan_final(const __hip_bfloat16* __restrict__ U,
                const float* __restrict__ Pk,
                const float* __restrict__ log_decay,
                __hip_bfloat16* __restrict__ S)
{
    const int c = blockIdx.x, b = blockIdx.y;
    const int d8 = threadIdx.x * 8;

    const float ld = log_decay[0];
    const float alpha = log1pf(__expf(ld));          // softplus
    const float ratio = __expf(-alpha);
    float dec = __expf(-alpha * (float)(c * CL));

    const float* pk = &Pk[((size_t)b * NC + c) * DD + d8];
    float run[8];
    float4 r0 = *(const float4*)pk;
    float4 r1 = *(const float4*)(pk + 4);
    run[0] = r0.x; run[1] = r0.y; run[2] = r0.z; run[3] = r0.w;
    run[4] = r1.x; run[5] = r1.y; run[6] = r1.z; run[7] = r1.w;

    const size_t base = ((size_t)b * TT + (size_t)c * CL) * DD + d8;
    const unsigned short* up = (const unsigned short*)U + base;
    unsigned short* sp = (unsigned short*)S + base;

    #pragma unroll 8
    for (int t = 0; t < CL; ++t) {
        uint4 raw = *(const uint4*)(up + (size_t)t * DD);
        unsigned int wds[4] = {raw.x, raw.y, raw.z, raw.w};
        uint4 o;
        unsigned int* ow = (unsigned int*)&o;
        #pragma unroll
        for (int k = 0; k < 4; ++k) {
            run[2 * k]     += bfbits2f((unsigned short)(wds[k] & 0xFFFF));
            run[2 * k + 1] += bfbits2f((unsigned short)(wds[k] >> 16));
            ow[k] = pack2(run[2 * k] * dec, run[2 * k + 1] * dec);
        }
        *(uint4*)(sp + (size_t)t * DD) = o;
        dec *= ratio;
    }
}

// ---------------------------------------------------------------------------
// Workspace: 39 MB. normed/S 32 MB | Pk 1 MB | Wg/Wv/Wo bf16 2 MB each.
// U (bf16, 32 MB) lives in d_out (fp32 64 MB); dead before gemm_out writes.
// ---------------------------------------------------------------------------
extern "C" void kernel_launch(void* const* d_in, const int* in_sizes, int n_in,
                              void* d_out, int out_size, void* d_ws, size_t ws_size,
                              hipStream_t stream)
{
    const float* x        = (const float*)d_in[0];
    const float* ln_w     = (const float*)d_in[1];
    const float* ln_b     = (const float*)d_in[2];
    const float* gate_w   = (const float*)d_in[3];
    const float* gate_b   = (const float*)d_in[4];
    const float* value_w  = (const float*)d_in[5];
    const float* value_b  = (const float*)d_in[6];
    const float* out_w    = (const float*)d_in[7];
    const float* out_b    = (const float*)d_in[8];
    const float* log_dec  = (const float*)d_in[9];
    float* out = (float*)d_out;

    char* ws = (char*)d_ws;
    const size_t MB = 1024 * 1024;
    __hip_bfloat16* normed = (__hip_bfloat16*)(ws);           // 32 MB, reused as S
    __hip_bfloat16* S      = (__hip_bfloat16*)(ws);
    float*          Pk     = (float*)(ws + 32 * MB);          // 1 MB
    __hip_bfloat16* Wg16   = (__hip_bfloat16*)(ws + 33 * MB); // 2 MB
    __hip_bfloat16* Wv16   = (__hip_bfloat16*)(ws + 35 * MB); // 2 MB
    __hip_bfloat16* Wo16   = (__hip_bfloat16*)(ws + 37 * MB); // 2 MB
    __hip_bfloat16* U      = (__hip_bfloat16*)d_out;          // scratch in d_out

    // 0. weight conversion fp32 -> bf16 (single launch)
    convert_w3<<<dim3(3072), dim3(256), 0, stream>>>(
        gate_w, value_w, out_w, Wg16, Wv16, Wo16);

    // 1. LayerNorm: x -> normed (bf16), wave-per-row
    ln_kernel<<<dim3(MM / 4), dim3(256), 0, stream>>>(x, ln_w, ln_b, normed);

    // 2. fused gate+value projections + gating + chunk sums: normed -> U, Pk
    dual_gemm_gate<<<dim3(MM / 128, DD / 128), dim3(256), 0, stream>>>(
        normed, Wg16, Wv16, gate_b, value_b, U, Pk, MM, DD, DD);

    // 3. chunk-offset exclusive scan (in place over Pk), then within-chunk
    //    inclusive scan + decay: U -> S (overwrites normed; it's dead)
    scan_offsets<<<dim3(NC), dim3(256), 0, stream>>>(Pk);
    scan_final<<<dim3(NC, BB), dim3(128), 0, stream>>>(U, Pk, log_dec, S);

    // 4. out = x + S @ out_w^T + out_b   (overwrites U; it's dead)
    gemm_out<<<dim3(MM / 128, DD / 128), dim3(256), 0, stream>>>(
        S, Wo16, out_b, x, out, MM, DD, DD);
}